// Round 2
// baseline (121.433 us; speedup 1.0000x reference)
//
#include <hip/hip_runtime.h>

constexpr int L = 12;
constexpr int B = 4, T = 2048, H = 16, D = 64;
constexpr int NPOS = B * T * H;                     // 131072 positions (b,t,h)
constexpr long long SLAYER = (long long)NPOS * D;   // elements per layer slice
constexpr int P = 16;                               // positions per wave

// Mt[c][d] = M[d][c] = sum_e Wq[e][d] * Wk[e][c]   (score_l = x^T M y_l)
// Transposed so lane c of the main kernel reads its column contiguously.
__global__ __launch_bounds__(64) void cla_precompute_Mt(
    const float* __restrict__ Wq, const float* __restrict__ Wk,
    float* __restrict__ Mt) {
  const int d = blockIdx.x;    // 64 blocks
  const int c = threadIdx.x;   // 64 threads
  float acc = 0.f;
  #pragma unroll
  for (int e = 0; e < D; ++e)
    acc = fmaf(Wq[e * D + d], Wk[e * D + c], acc);
  Mt[c * D + d] = acc;
}

// DPP-based full-wave (64-lane) sum, result broadcast via readlane.
// row_shr:1/2/4/8 then row_bcast15 (rows 1,3) + row_bcast31 (rows 2,3);
// total lands in lane 63. All VALU pipe — no LDS ops.
template <int CTRL, int ROWM>
__device__ __forceinline__ float dpp_add(float x) {
  int moved = __builtin_amdgcn_update_dpp(0, __float_as_int(x), CTRL, ROWM, 0xF,
                                          false);
  return x + __int_as_float(moved);
}

__device__ __forceinline__ float wave_sum_bcast(float x) {
  x = dpp_add<0x111, 0xF>(x);  // row_shr:1
  x = dpp_add<0x112, 0xF>(x);  // row_shr:2
  x = dpp_add<0x114, 0xF>(x);  // row_shr:4
  x = dpp_add<0x118, 0xF>(x);  // row_shr:8   -> lane15 of each row = row sum
  x = dpp_add<0x142, 0xA>(x);  // row_bcast15 -> lane31 = r0+r1, lane63 = r2+r3
  x = dpp_add<0x143, 0xC>(x);  // row_bcast31 -> lane63 = total
  return __int_as_float(__builtin_amdgcn_readlane(__float_as_int(x), 63));
}

__global__ __launch_bounds__(256) void cla_main(
    const float* __restrict__ cur, const float* __restrict__ all,
    const float* __restrict__ Mt, const float* __restrict__ scales,
    const float* __restrict__ temperature, float* __restrict__ out) {
  const int lane = threadIdx.x & 63;
  const int wloc = __builtin_amdgcn_readfirstlane(threadIdx.x >> 6);
  const int wid  = blockIdx.x * 4 + wloc;   // global wave id (uniform)

  // This lane's M column: M[d][lane], d = 0..63 — 64 VGPRs, loaded once,
  // reused for P positions. (16 scattered b128 reads, L1-resident.)
  float Mc[D];
  {
    const float4* mt = (const float4*)(Mt + lane * D);
    #pragma unroll
    for (int c = 0; c < 16; ++c) {
      const float4 m = mt[c];
      Mc[4 * c + 0] = m.x;
      Mc[4 * c + 1] = m.y;
      Mc[4 * c + 2] = m.z;
      Mc[4 * c + 3] = m.w;
    }
  }

  const float inv_scale = 1.0f / (8.0f * fabsf(temperature[0]));  // sqrt(64)=8
  float scl[L];
  #pragma unroll
  for (int l = 0; l < L; ++l) scl[l] = scales[l];

  const int pos0 = wid * P;
  for (int it = 0; it < P; ++it) {
    const int pos = pos0 + it;          // wave-uniform
    const size_t pbase = (size_t)pos * D;

    // v[lane] = sum_d x[d] * M[d][lane]; x is wave-uniform -> scalar loads.
    const float4* xp = (const float4*)(cur + pbase);
    float v = 0.f;
    #pragma unroll
    for (int dc = 0; dc < 4; ++dc) {
      const float4 a = xp[4 * dc + 0];
      const float4 b = xp[4 * dc + 1];
      const float4 c = xp[4 * dc + 2];
      const float4 d = xp[4 * dc + 3];
      v = fmaf(a.x, Mc[16 * dc + 0], v);
      v = fmaf(a.y, Mc[16 * dc + 1], v);
      v = fmaf(a.z, Mc[16 * dc + 2], v);
      v = fmaf(a.w, Mc[16 * dc + 3], v);
      v = fmaf(b.x, Mc[16 * dc + 4], v);
      v = fmaf(b.y, Mc[16 * dc + 5], v);
      v = fmaf(b.z, Mc[16 * dc + 6], v);
      v = fmaf(b.w, Mc[16 * dc + 7], v);
      v = fmaf(c.x, Mc[16 * dc + 8], v);
      v = fmaf(c.y, Mc[16 * dc + 9], v);
      v = fmaf(c.z, Mc[16 * dc + 10], v);
      v = fmaf(c.w, Mc[16 * dc + 11], v);
      v = fmaf(d.x, Mc[16 * dc + 12], v);
      v = fmaf(d.y, Mc[16 * dc + 13], v);
      v = fmaf(d.z, Mc[16 * dc + 14], v);
      v = fmaf(d.w, Mc[16 * dc + 15], v);
    }

    // y_l[lane] for all layers (single pass over all_layers)
    float yv[L];
    #pragma unroll
    for (int l = 0; l < L; ++l)
      yv[l] = all[(size_t)l * SLAYER + pbase + lane];

    // scores: full-wave dot products, DPP reduce (independent chains)
    float sc[L];
    #pragma unroll
    for (int l = 0; l < L; ++l)
      sc[l] = wave_sum_bcast(v * yv[l]) * inv_scale;

    // softmax over L (redundant per lane; values wave-uniform)
    float mx = sc[0];
    #pragma unroll
    for (int l = 1; l < L; ++l) mx = fmaxf(mx, sc[l]);
    float sum = 0.f;
    #pragma unroll
    for (int l = 0; l < L; ++l) { sc[l] = __expf(sc[l] - mx); sum += sc[l]; }
    const float inv_sum = 1.0f / sum;

    float w[L];
    float ssum = 0.f;
    #pragma unroll
    for (int l = 0; l < L; ++l) {
      w[l] = sc[l] * inv_sum * scl[l];
      ssum += w[l];
    }
    const float r = 1.0f / (ssum + 1e-6f);

    float o = 0.f;
    #pragma unroll
    for (int l = 0; l < L; ++l) o = fmaf(w[l] * r * scl[l], yv[l], o);
    out[pbase + lane] = o;
  }
}

extern "C" void kernel_launch(void* const* d_in, const int* in_sizes, int n_in,
                              void* d_out, int out_size, void* d_ws, size_t ws_size,
                              hipStream_t stream) {
  const float* cur    = (const float*)d_in[0];
  const float* all    = (const float*)d_in[1];
  const float* Wq     = (const float*)d_in[2];
  const float* Wk     = (const float*)d_in[3];
  const float* scales = (const float*)d_in[4];
  const float* temp   = (const float*)d_in[5];
  float* Mt = (float*)d_ws;   // 16 KB scratch: (Wq^T Wk)^T

  cla_precompute_Mt<<<64, 64, 0, stream>>>(Wq, Wk, Mt);

  const int nwaves  = NPOS / P;          // 8192 waves
  const int nblocks = nwaves / 4;        // 256-thread blocks = 4 waves
  cla_main<<<nblocks, 256, 0, stream>>>(cur, all, Mt, scales, temp,
                                        (float*)d_out);
}